// Round 12
// baseline (132.817 us; speedup 1.0000x reference)
//
#include <hip/hip_runtime.h>
#include <hip/hip_bf16.h>

// LSTM: B=4096, T=200, I=2, H=64, O=2
// grid = 256 blocks x 256 threads (4 waves). ZERO BARRIERS in the recurrence:
// each wave owns 4 batch rows (blockIdx*16 + 4w .. +3) and computes the FULL
// 64-unit recurrence itself -> 1024 fully independent waves, 1 per SIMD.
// R3/R5/R7/R8/R11 showed every barrier-clocked schedule pays 550-900 cyc/step
// idle; this removes the barrier entirely.
//
// Static-index mappings (rule #20 safe):
//  * A-row map A'[p] = h[p>>2]: D row 4g+r = batch row g for ALL regs r ->
//    lane (g,c)'s runtime g lives in the HARDWARE row dim; reg index static(0).
//  * Gate-interleaved B-tiles: tile j <-> (gate m=j&3, unit-block ub=j>>2),
//    B col c = lane's c: gate-row gr = 64m + 16ub + c. Lane (g,c) owns
//    (batch row 4w+g, units 16s+c, s=0..3) and extracts acc[4s+m][0] with
//    compile-time tile indices. No cndmask, no rotation.
//  * W_hh in registers: 16 tiles x 2 k-halves = 128 VGPRs. Proj coeffs
//    cw0/cw1/cbs[16] share the tile index (unit 16(j>>2)+c, gate j&3).
// Per step/wave: 2 ds_read_b128 (h) + 1 b64 (x) + 32 MFMA + 48 proj VALU +
// 4 fused ACT chains (20 exp + 8 rcp) + 4 ds_write_b16. The only serial
// handoff is the in-wave LDS write->read (compiler emits lgkmcnt).
// hsh padded [4][80] -> A-reads and h-writes max 2-way bank alias (free).
// Activation algebra (gate scales folded into weights: i,f,o: -log2e,
// g: 2*log2e):
//   c' = (c*P + (Eg-1)(1+Ef)) * rcp(P*(1+Ef)),  P = (1+Ei)(Eg+1)
//   h  = (Ec-1) * rcp((1+Eo)(Ec+1)),            Ec = 2^(2*log2e*c)
// FC epilogue fully in-register: per-lane partials + __shfl_xor reduce.

#define B_ 4096
#define T_ 200

typedef _Float16 half8 __attribute__((ext_vector_type(8)));
typedef float f32x4 __attribute__((ext_vector_type(4)));

#define K1f 1.4426950408889634f   // log2(e)
#define K2f 2.8853900817779268f   // 2*log2(e)

__global__ __launch_bounds__(256, 1) void lstm_kernel(
    const float* __restrict__ x,     // [4096][200][2]
    const float* __restrict__ W_ih,  // [256][2]
    const float* __restrict__ W_hh,  // [256][64]
    const float* __restrict__ b_ih,  // [256]
    const float* __restrict__ b_hh,  // [256]
    const float* __restrict__ W_fc,  // [2][64]
    const float* __restrict__ b_fc,  // [2]
    float* __restrict__ out)         // [4096][2]
{
    __shared__ float xs[16][404];     // x tile (float4-aligned rows)
    __shared__ _Float16 hsh[4][4][80]; // per-wave h: [wave][row g][unit], pad 64->80

    const int tid  = threadIdx.x;
    const int lane = tid & 63;
    const int w    = tid >> 6;      // wave 0..3 (independent LSTM)
    const int c    = lane & 15;     // B-col / unit low index
    const int g    = lane >> 4;     // lane group = this lane's local batch row
    const int r0   = blockIdx.x * 16;

    // ---- stage x tile (coalesced float4): 16 rows x 100 float4 ----
    for (int i4 = tid; i4 < 1600; i4 += 256) {
        const int row = i4 / 100;
        const int j4  = i4 - row * 100;
        reinterpret_cast<float4*>(&xs[row][0])[j4] =
            reinterpret_cast<const float4*>(x + (size_t)(r0 + row) * 400)[j4];
    }
    // ---- zero hsh: 4*4*80 f16 = 1280 f16 = 2560 B = 640 dwords (verified!) ----
    for (int i = tid; i < 640; i += 256)
        reinterpret_cast<unsigned int*>(&hsh[0][0][0])[i] = 0u;
    __syncthreads();   // ONE-TIME staging barrier; none in the loop

    // ---- W_hh B-fragments (f16, gate-scaled) + proj coeffs, registers ----
    // B-frag (16x16x32): lane l -> col = l&15 (=c), k = (l>>4)*8 + e (=g*8+e)
    half8 bfrag[16][2];
    float cw0[16], cw1[16], cbs[16];   // index j: unit 16*(j>>2)+c, gate j&3
    #pragma unroll
    for (int j = 0; j < 16; ++j) {
        const int m  = j & 3;           // gate: 0=i,1=f,2=g,3=o
        const int ub = j >> 2;          // unit block
        const float sc = (m == 2) ? K2f : -K1f;
        const int gr = 64 * m + 16 * ub + c;   // gate row (this lane's B col)
        #pragma unroll
        for (int kt = 0; kt < 2; ++kt) {
            const float* p = W_hh + gr * 64 + kt * 32 + g * 8;
            const float4 lo = reinterpret_cast<const float4*>(p)[0];
            const float4 hi = reinterpret_cast<const float4*>(p)[1];
            half8 f;
            f[0] = (_Float16)(lo.x * sc); f[1] = (_Float16)(lo.y * sc);
            f[2] = (_Float16)(lo.z * sc); f[3] = (_Float16)(lo.w * sc);
            f[4] = (_Float16)(hi.x * sc); f[5] = (_Float16)(hi.y * sc);
            f[6] = (_Float16)(hi.z * sc); f[7] = (_Float16)(hi.w * sc);
            bfrag[j][kt] = f;
        }
        cw0[j] = W_ih[gr * 2 + 0] * sc;
        cw1[j] = W_ih[gr * 2 + 1] * sc;
        cbs[j] = (b_ih[gr] + b_hh[gr]) * sc;
    }

    const int arow = c >> 2;                    // A'[p] = h[p>>2]
    const _Float16* hrd = &hsh[w][arow][0];     // A-frag source (row p>>2)
    _Float16*       hwr = &hsh[w][g][0];        // this lane writes row g

    float cst[4] = {0.f, 0.f, 0.f, 0.f};        // c-state: units 16s+c of row g
    float hvk[4];                               // last h values (for FC)

    for (int t = 0; t < T_; ++t) {
        // A-frag: lane l -> A'[l&15][k=(l>>4)*8+e] = h[(l&15)>>2][g*8+e] (+32)
        const half8 a0 = *reinterpret_cast<const half8*>(hrd + g * 8);
        const half8 a1 = *reinterpret_cast<const half8*>(hrd + 32 + g * 8);
        const float2 xv = *reinterpret_cast<const float2*>(&xs[4 * w + g][2 * t]);

        f32x4 acc[16];
        #pragma unroll
        for (int j = 0; j < 16; ++j) {
            f32x4 z = {0.f, 0.f, 0.f, 0.f};
            z = __builtin_amdgcn_mfma_f32_16x16x32_f16(a0, bfrag[j][0], z, 0, 0, 0);
            z = __builtin_amdgcn_mfma_f32_16x16x32_f16(a1, bfrag[j][1], z, 0, 0, 0);
            acc[j] = z;
        }

        // ---- 4 ACT chains: (row g, unit 16s+c), all indices static ----
        #pragma unroll
        for (int s = 0; s < 4; ++s) {
            float pre[4];
            #pragma unroll
            for (int m = 0; m < 4; ++m) {
                const int j = 4 * s + m;
                pre[m] = fmaf(xv.y, cw1[j], fmaf(xv.x, cw0[j], cbs[j])) + acc[j][0];
            }
            const float Ei = __builtin_amdgcn_exp2f(pre[0]);  // e^{-ip}
            const float Ef = __builtin_amdgcn_exp2f(pre[1]);  // e^{-fp}
            const float Eg = __builtin_amdgcn_exp2f(pre[2]);  // e^{2 gp}
            const float Eo = __builtin_amdgcn_exp2f(pre[3]);  // e^{-op}
            const float fEf = 1.0f + Ef;
            const float P   = (1.0f + Ei) * (Eg + 1.0f);
            const float r1  = __builtin_amdgcn_rcpf(P * fEf);
            const float cv  = fmaf(cst[s], P, (Eg - 1.0f) * fEf) * r1;
            cst[s] = cv;
            const float Ec = __builtin_amdgcn_exp2f(fminf(K2f * cv, 60.0f));
            const float r2 = __builtin_amdgcn_rcpf((1.0f + Eo) * (Ec + 1.0f));
            const float hv = (Ec - 1.0f) * r2;
            hvk[s] = hv;
            hwr[16 * s + c] = (_Float16)hv;   // h[g][16s+c]; next-iter read is
                                              // same-wave; compiler emits lgkmcnt
        }
    }

    // ---- FC epilogue, in-register: out[row][o] = b_fc[o] + sum_u Wfc[o][u]*h ----
    float p0 = 0.f, p1 = 0.f;
    #pragma unroll
    for (int s = 0; s < 4; ++s) {
        p0 = fmaf(W_fc[16 * s + c],      hvk[s], p0);
        p1 = fmaf(W_fc[64 + 16 * s + c], hvk[s], p1);
    }
    #pragma unroll
    for (int mk = 1; mk < 16; mk <<= 1) {   // reduce over c (lanes 16g..16g+15)
        p0 += __shfl_xor(p0, mk);
        p1 += __shfl_xor(p1, mk);
    }
    if (c == 0) {
        const int row = r0 + 4 * w + g;
        out[row * 2 + 0] = p0 + b_fc[0];
        out[row * 2 + 1] = p1 + b_fc[1];
    }
}

extern "C" void kernel_launch(void* const* d_in, const int* in_sizes, int n_in,
                              void* d_out, int out_size, void* d_ws, size_t ws_size,
                              hipStream_t stream) {
    const float* x    = (const float*)d_in[0];
    const float* W_ih = (const float*)d_in[1];
    const float* W_hh = (const float*)d_in[2];
    const float* b_ih = (const float*)d_in[3];
    const float* b_hh = (const float*)d_in[4];
    const float* W_fc = (const float*)d_in[5];
    const float* b_fc = (const float*)d_in[6];
    float* out = (float*)d_out;

    lstm_kernel<<<B_ / 16, 256, 0, stream>>>(x, W_ih, W_hh, b_ih, b_hh, W_fc, b_fc, out);
}